// Round 1
// baseline (224.936 us; speedup 1.0000x reference)
//
#include <hip/hip_runtime.h>

#define BLOCK 256

__global__ __launch_bounds__(BLOCK) void gauss_cov_kernel(
    const float4* __restrict__ quat,
    const float*  __restrict__ log_scale,
    float*        __restrict__ out,
    int n)
{
    __shared__ float sm[BLOCK * 9];
    const int tid = threadIdx.x;
    const long long i = (long long)blockIdx.x * BLOCK + tid;
    const bool full_block = ((long long)(blockIdx.x + 1) * BLOCK) <= (long long)n;

    // ---- load log_scale (coalesced via LDS stage) ----
    float ls0 = 0.f, ls1 = 0.f, ls2 = 0.f;
    if (full_block) {
        const long long base3 = (long long)blockIdx.x * BLOCK * 3;
        #pragma unroll
        for (int k = 0; k < 3; ++k)
            sm[k * BLOCK + tid] = log_scale[base3 + k * BLOCK + tid];
        __syncthreads();
        ls0 = sm[tid * 3 + 0];
        ls1 = sm[tid * 3 + 1];
        ls2 = sm[tid * 3 + 2];
        __syncthreads();
    } else if (i < n) {
        ls0 = log_scale[3 * i + 0];
        ls1 = log_scale[3 * i + 1];
        ls2 = log_scale[3 * i + 2];
    }

    // ---- load quaternion (float4, coalesced) ----
    float c[9];
    if (i < n) {
        const float4 q4 = quat[i];
        const float dot = q4.x * q4.x + q4.y * q4.y + q4.z * q4.z + q4.w * q4.w;
        const float norm = sqrtf(dot);
        const float inv = 1.0f / fmaxf(norm, 1e-12f);
        const float qw = q4.x * inv;
        const float qx = q4.y * inv;
        const float qy = q4.z * inv;
        const float qz = q4.w * inv;

        const float r00 = 1.f - 2.f * (qy * qy + qz * qz);
        const float r01 = 2.f * (qx * qy - qz * qw);
        const float r02 = 2.f * (qx * qz + qy * qw);
        const float r10 = 2.f * (qx * qy + qz * qw);
        const float r11 = 1.f - 2.f * (qx * qx + qz * qz);
        const float r12 = 2.f * (qy * qz - qx * qw);
        const float r20 = 2.f * (qx * qz - qy * qw);
        const float r21 = 2.f * (qy * qz + qx * qw);
        const float r22 = 1.f - 2.f * (qx * qx + qy * qy);

        const float s0 = expf(ls0);
        const float s1 = expf(ls1);
        const float s2 = expf(ls2);

        // cov[i][k] = sum_j s_j * R[i][j] * R[k][j]
        c[0] = s0 * r00 * r00 + s1 * r01 * r01 + s2 * r02 * r02;
        c[1] = s0 * r00 * r10 + s1 * r01 * r11 + s2 * r02 * r12;
        c[2] = s0 * r00 * r20 + s1 * r01 * r21 + s2 * r02 * r22;
        c[3] = c[1];
        c[4] = s0 * r10 * r10 + s1 * r11 * r11 + s2 * r12 * r12;
        c[5] = s0 * r10 * r20 + s1 * r11 * r21 + s2 * r12 * r22;
        c[6] = c[2];
        c[7] = c[5];
        c[8] = s0 * r20 * r20 + s1 * r21 * r21 + s2 * r22 * r22;
    }

    // ---- store covariance ----
    if (full_block) {
        // stage in LDS (stride 9 -> 2-way bank aliasing, free), then 9
        // fully-coalesced stride-1 dword stores
        #pragma unroll
        for (int j = 0; j < 9; ++j)
            sm[tid * 9 + j] = c[j];
        __syncthreads();
        const long long base9 = (long long)blockIdx.x * BLOCK * 9;
        #pragma unroll
        for (int k = 0; k < 9; ++k)
            out[base9 + k * BLOCK + tid] = sm[k * BLOCK + tid];
    } else if (i < n) {
        #pragma unroll
        for (int j = 0; j < 9; ++j)
            out[i * 9 + j] = c[j];
    }
}

extern "C" void kernel_launch(void* const* d_in, const int* in_sizes, int n_in,
                              void* d_out, int out_size, void* d_ws, size_t ws_size,
                              hipStream_t stream) {
    const float4* quat      = (const float4*)d_in[0];
    const float*  log_scale = (const float*)d_in[1];
    float*        out       = (float*)d_out;
    const int n = in_sizes[0] / 4;  // quaternion is (N,4)

    const int grid = (n + BLOCK - 1) / BLOCK;
    gauss_cov_kernel<<<grid, BLOCK, 0, stream>>>(quat, log_scale, out, n);
}